// Round 8
// baseline (3789.414 us; speedup 1.0000x reference)
//
#include <hip/hip_runtime.h>
#include <stdint.h>

typedef __bf16 bf16;
typedef __attribute__((ext_vector_type(8))) __bf16 bf16x8;
typedef __attribute__((ext_vector_type(4))) float f32x4;

#define GRU_H 2048
#define ODIM 96
#define PADX 128
#define BATCH 1024
#define TSTEPS 25

__device__ __forceinline__ float sigm(float x) { return 1.f / (1.f + __expf(-x)); }

__device__ __forceinline__ void gload16(const void* g, void* l) {
  __builtin_amdgcn_global_load_lds((const __attribute__((address_space(1))) uint32_t*)g,
                                   (__attribute__((address_space(3))) uint32_t*)l, 16, 0, 0);
}

// ---------------- init / convert kernels ----------------
__global__ void k_cvt(const float* __restrict__ s, bf16* __restrict__ d, int n) {
  int stride = gridDim.x * blockDim.x;
  for (int i = blockIdx.x * blockDim.x + threadIdx.x; i < n; i += stride)
    d[i] = (bf16)s[i];
}

__global__ void k_cvt_pad(const float* __restrict__ s, bf16* __restrict__ d,
                          int rows, int cin, int cout) {
  int n = rows * cout;
  int stride = gridDim.x * blockDim.x;
  for (int i = blockIdx.x * blockDim.x + threadIdx.x; i < n; i += stride) {
    int r = i / cout, c = i - r * cout;
    d[i] = (c < cin) ? (bf16)s[r * cin + c] : (bf16)0.f;
  }
}

__global__ void k_init_h(const float* __restrict__ s, float* __restrict__ hf,
                         bf16* __restrict__ hb, int n) {
  int stride = gridDim.x * blockDim.x;
  for (int i = blockIdx.x * blockDim.x + threadIdx.x; i < n; i += stride) {
    float v = s[i];
    hf[i] = v;
    hb[i] = (bf16)v;
  }
}

// Weight fragment pre-swizzle: dst[bnT][g][k64][wn][kf][lane l][e] (bf16),
// where SOURCE row = g*2048 + bnT*64 + wn*16 + (l&15)  (gate-major rows!),
// k = k64*64 + kf*32 + (l>>4)*8 + e.
// A wave's B-fragment (g, k64, kf) is then 64 lanes x 16B contiguous.
__global__ __launch_bounds__(256) void k_cvt_wfrag(const float* __restrict__ src,
                                                   bf16* __restrict__ dst,
                                                   int K, int Ksrc) {
  const int bnT = blockIdx.x;               // 0..31
  const int K64 = K / 64;
  const int g = blockIdx.y / K64;
  const int k64 = blockIdx.y - g * K64;
  const int t = threadIdx.x;
  size_t dbase = ((size_t)(bnT * 3 + g) * K64 + k64) * 4096;
  int e0 = t * 16;                          // 16 elements per thread
  bf16 tmp[16];
#pragma unroll
  for (int i = 0; i < 16; ++i) {
    int el = e0 + i;
    int wn = el >> 10;
    int kf = (el >> 9) & 1;
    int l = (el >> 3) & 63;
    int e = el & 7;
    int row = g * GRU_H + bnT * 64 + wn * 16 + (l & 15);   // FIX: + g*GRU_H
    int k = k64 * 64 + kf * 32 + (l >> 4) * 8 + e;
    float v = (k < Ksrc) ? src[(size_t)row * Ksrc + k] : 0.f;
    tmp[i] = (bf16)v;
  }
  char* dp = (char*)(dst + dbase + e0);
  ((int4*)dp)[0] = ((int4*)tmp)[0];
  ((int4*)dp)[1] = ((int4*)tmp)[1];
}

// ---------------- fused GRU layer kernel ----------------
// 512 thr = 8 waves (wm = w&1 row-half of 64, wn = w>>1 16-col slice).
// Block tile 128 rows x 64 H-cols x 3 gates; grid (32,8) = 256 = 1 block/CU,
// 2 waves/SIMD (launch_bounds(512,2) -> VGPR cap 256).
// A (activations) staged in LDS (2 x 16KB, depth-1, global_load_lds, XOR
// swizzle on source per rule #21). B (weights) loaded straight from the
// pre-swizzled fragment layout into registers, double-buffered, depth-1.
// One {vmcnt(0); s_barrier} per K-step; loads issued a full step before use.
// LDS traffic/step: 16KB write + 64KB read (< MFMA pipe) -> MFMA-bound.
__global__ __launch_bounds__(512, 2) void k_gru(
    const bf16* __restrict__ xb, int kx,          // x input [1024][kx], kx=128 or 2048
    const bf16* __restrict__ hb,                  // h_prev bf16 [1024][2048]
    const bf16* __restrict__ wihf,                // frag layout, K64ih = kx/64
    const bf16* __restrict__ whhf,                // frag layout, K64hh = 32
    const float* __restrict__ bih, const float* __restrict__ bhh,
    const float* __restrict__ hprevf,             // h_prev fp32 master
    float* __restrict__ hnewf, bf16* __restrict__ hnewb) {
  __shared__ alignas(16) char sm[2][16384];       // A only: 128 rows x 64 bf16

  const int tid = threadIdx.x;
  const int l = tid & 63;
  const int w = tid >> 6;
  const int wm = w & 1, wn = w >> 1;
  const int wb = tid & ~63;
  const int bnT = blockIdx.x;
  const int bn0 = bnT * 64;
  const int bm0 = blockIdx.y * 128;
  const int lm = l >> 4, ln = l & 15;
  char* sm0 = &sm[0][0];

  const int S1 = GRU_H / 64;                      // 32 hh steps
  const int S2 = kx / 64;                         // 2 or 32 ih steps
  const int S = S1 + S2;                          // 34 or 64 (even)
  const int K64hh = GRU_H / 64, K64ih = kx / 64;

  f32x4 accR[4] = {};
  f32x4 accZ[4] = {};
  f32x4 accNH[4] = {};
  f32x4 accNI[4] = {};

  // A staging bases: chunk c = it*512 + tid, row = c>>3 (steps of 64 per it),
  // slot = (c&7)^(row&7) is it-invariant.
  const bf16* pAhh[2]; const bf16* pAih[2]; int ldsA[2];
#pragma unroll
  for (int i = 0; i < 2; ++i) {
    int c = i * 512 + tid, row = c >> 3, slot = (c & 7) ^ (row & 7);
    pAhh[i] = hb + (size_t)(bm0 + row) * GRU_H + slot * 8;
    pAih[i] = xb + (size_t)(bm0 + row) * kx + slot * 8;
    ldsA[i] = (i * 512 + wb) << 4;
  }
  // B fragment bases (per wave)
  const bf16* pWhh = whhf + (size_t)bnT * 3 * K64hh * 4096 + wn * 1024 + l * 8;
  const bf16* pWih = wihf + (size_t)bnT * 3 * K64ih * 4096 + wn * 1024 + l * 8;

  auto stageA = [&](int sp, char* sb) {
    if (sp < S1) {
      int koff = sp * 64;
#pragma unroll
      for (int i = 0; i < 2; ++i) gload16(pAhh[i] + koff, sb + ldsA[i]);
    } else {
      int koff = (sp - S1) * 64;
#pragma unroll
      for (int i = 0; i < 2; ++i) gload16(pAih[i] + koff, sb + ldsA[i]);
    }
  };
  auto loadB = [&](int sp, bf16x8 (&B)[6]) {
    if (sp < S1) {
      const bf16* p = pWhh + (size_t)sp * 4096;
#pragma unroll
      for (int g = 0; g < 3; ++g)
#pragma unroll
        for (int kf = 0; kf < 2; ++kf)
          B[g * 2 + kf] = *(const bf16x8*)(p + (size_t)g * K64hh * 4096 + kf * 512);
    } else {
      const bf16* p = pWih + (size_t)(sp - S1) * 4096;
#pragma unroll
      for (int g = 0; g < 3; ++g)
#pragma unroll
        for (int kf = 0; kf < 2; ++kf)
          B[g * 2 + kf] = *(const bf16x8*)(p + (size_t)g * K64ih * 4096 + kf * 512);
    }
  };

  auto computeStep = [&](const char* bp, bf16x8 (&B)[6], f32x4 (&accN)[4]) {
#pragma unroll
    for (int kf = 0; kf < 2; ++kf) {
      const int pos = ((kf * 4 + lm) ^ (ln & 7)) << 4;
      bf16x8 af[4];
#pragma unroll
      for (int mf = 0; mf < 4; ++mf)
        af[mf] = *(const bf16x8*)(bp + (wm * 64 + mf * 16 + ln) * 128 + pos);
#pragma unroll
      for (int mf = 0; mf < 4; ++mf)
        accR[mf] = __builtin_amdgcn_mfma_f32_16x16x32_bf16(af[mf], B[0 + kf], accR[mf], 0, 0, 0);
#pragma unroll
      for (int mf = 0; mf < 4; ++mf)
        accZ[mf] = __builtin_amdgcn_mfma_f32_16x16x32_bf16(af[mf], B[2 + kf], accZ[mf], 0, 0, 0);
#pragma unroll
      for (int mf = 0; mf < 4; ++mf)
        accN[mf] = __builtin_amdgcn_mfma_f32_16x16x32_bf16(af[mf], B[4 + kf], accN[mf], 0, 0, 0);
    }
  };

  bf16x8 B0[6], B1[6];

  auto body = [&](int s, char* bufR, char* bufW, bf16x8 (&Bc)[6], bf16x8 (&Bn)[6]) {
    // All my loads (A(s) stage + B(s) frags) issued one full step ago.
    asm volatile("s_waitcnt vmcnt(0)" ::: "memory");
    __builtin_amdgcn_s_barrier();                  // A(s) visible; WAR-safe for bufW
    if (s + 1 < S) { loadB(s + 1, Bn); stageA(s + 1, bufW); }
    __builtin_amdgcn_s_setprio(1);
    if (s < S1) computeStep(bufR, Bc, accNH);
    else        computeStep(bufR, Bc, accNI);
    __builtin_amdgcn_s_setprio(0);
  };

  // prologue: depth-1 fill
  loadB(0, B0);
  stageA(0, sm0);

  for (int s = 0; s < S; s += 2) {
    body(s + 0, sm0,         sm0 + 16384, B0, B1);
    body(s + 1, sm0 + 16384, sm0,         B1, B0);
  }

  // ---- GRU epilogue ----
  {
    int j = bn0 + wn * 16 + ln;
    float br = bih[j] + bhh[j];
    float bz = bih[GRU_H + j] + bhh[GRU_H + j];
    float bin = bih[2 * GRU_H + j];
    float bhn = bhh[2 * GRU_H + j];
#pragma unroll
    for (int mf = 0; mf < 4; ++mf) {
#pragma unroll
      for (int rr = 0; rr < 4; ++rr) {
        int m = bm0 + wm * 64 + mf * 16 + lm * 4 + rr;
        size_t idx = (size_t)m * GRU_H + j;
        float hp = hprevf[idx];
        float rg = sigm(accR[mf][rr] + br);
        float zg = sigm(accZ[mf][rr] + bz);
        float ng = tanhf(accNI[mf][rr] + bin + rg * (accNH[mf][rr] + bhn));
        float hn = (1.f - zg) * ng + zg * hp;
        hnewf[idx] = hn;
        hnewb[idx] = (bf16)hn;
      }
    }
  }
}

// ---------------- FC (split-K) ----------------
__global__ __launch_bounds__(256, 1) void k_fc_part(const bf16* __restrict__ h1b,
                                                    const bf16* __restrict__ wfc,
                                                    float* __restrict__ part) {
  const int kc = blockIdx.x;
  const int mt = blockIdx.y;
  const int l = threadIdx.x & 63, w = threadIdx.x >> 6;
  const int lm = l >> 4, ln = l & 15;
  const int m0 = mt * 64 + w * 16;
  const int k0 = kc * 128;
  f32x4 acc[6] = {};
#pragma unroll
  for (int kf = 0; kf < 4; ++kf) {
    bf16x8 a = *(const bf16x8*)&h1b[(size_t)(m0 + ln) * GRU_H + k0 + kf * 32 + lm * 8];
#pragma unroll
    for (int nf = 0; nf < 6; ++nf) {
      bf16x8 b = *(const bf16x8*)&wfc[(size_t)(nf * 16 + ln) * GRU_H + k0 + kf * 32 + lm * 8];
      acc[nf] = __builtin_amdgcn_mfma_f32_16x16x32_bf16(a, b, acc[nf], 0, 0, 0);
    }
  }
  float* base = part + (size_t)kc * (BATCH * ODIM);
#pragma unroll
  for (int nf = 0; nf < 6; ++nf)
#pragma unroll
    for (int rr = 0; rr < 4; ++rr)
      base[(size_t)(m0 + lm * 4 + rr) * ODIM + nf * 16 + ln] = acc[nf][rr];
}

__global__ void k_fc_red(const float* __restrict__ part, const float* __restrict__ bfc,
                         float* __restrict__ dout, bf16* __restrict__ decb, int t) {
  int i = blockIdx.x * blockDim.x + threadIdx.x;
  if (i >= BATCH * ODIM) return;
  int m = i / ODIM, n = i - m * ODIM;
  float s = bfc[n];
#pragma unroll
  for (int kc = 0; kc < 16; ++kc) s += part[(size_t)kc * (BATCH * ODIM) + i];
  s = sigm(s);
  dout[(size_t)m * (TSTEPS * ODIM) + t * ODIM + n] = s;
  decb[m * PADX + n] = (bf16)s;
}

// ---------------- launch ----------------
extern "C" void kernel_launch(void* const* d_in, const int* in_sizes, int n_in,
                              void* d_out, int out_size, void* d_ws, size_t ws_size,
                              hipStream_t stream) {
  const float* input   = (const float*)d_in[0];
  const float* hiddens = (const float*)d_in[2];
  const float* W_ih0   = (const float*)d_in[3];
  const float* W_hh0   = (const float*)d_in[4];
  const float* b_ih0   = (const float*)d_in[5];
  const float* b_hh0   = (const float*)d_in[6];
  const float* W_ih1   = (const float*)d_in[7];
  const float* W_hh1   = (const float*)d_in[8];
  const float* b_ih1   = (const float*)d_in[9];
  const float* b_hh1   = (const float*)d_in[10];
  const float* W_fc    = (const float*)d_in[11];
  const float* b_fc    = (const float*)d_in[12];
  float* out = (float*)d_out;

  char* p = (char*)d_ws;
  auto take = [&](size_t n) { char* q = p; p += (n + 255) & ~(size_t)255; return q; };
  bf16* wih0f = (bf16*)take((size_t)3 * GRU_H * PADX * 2);
  bf16* whh0f = (bf16*)take((size_t)3 * GRU_H * GRU_H * 2);
  bf16* wih1f = (bf16*)take((size_t)3 * GRU_H * GRU_H * 2);
  bf16* whh1f = (bf16*)take((size_t)3 * GRU_H * GRU_H * 2);
  bf16* wfcb  = (bf16*)take((size_t)ODIM * GRU_H * 2);
  bf16* decb  = (bf16*)take((size_t)BATCH * PADX * 2);
  float* h0f[2], *h1f[2];
  bf16* h0b[2], *h1b[2];
  h0f[0] = (float*)take((size_t)BATCH * GRU_H * 4);
  h0f[1] = (float*)take((size_t)BATCH * GRU_H * 4);
  h1f[0] = (float*)take((size_t)BATCH * GRU_H * 4);
  h1f[1] = (float*)take((size_t)BATCH * GRU_H * 4);
  h0b[0] = (bf16*)take((size_t)BATCH * GRU_H * 2);
  h0b[1] = (bf16*)take((size_t)BATCH * GRU_H * 2);
  h1b[0] = (bf16*)take((size_t)BATCH * GRU_H * 2);
  h1b[1] = (bf16*)take((size_t)BATCH * GRU_H * 2);
  float* fcpart = (float*)take((size_t)16 * BATCH * ODIM * 4);

  // one-time (per launch) conversions: weights to fragment-major bf16
  k_cvt_wfrag<<<dim3(32, 3 * (PADX / 64)), 256, 0, stream>>>(W_ih0, wih0f, PADX, ODIM);
  k_cvt_wfrag<<<dim3(32, 3 * (GRU_H / 64)), 256, 0, stream>>>(W_hh0, whh0f, GRU_H, GRU_H);
  k_cvt_wfrag<<<dim3(32, 3 * (GRU_H / 64)), 256, 0, stream>>>(W_ih1, wih1f, GRU_H, GRU_H);
  k_cvt_wfrag<<<dim3(32, 3 * (GRU_H / 64)), 256, 0, stream>>>(W_hh1, whh1f, GRU_H, GRU_H);
  k_cvt<<<192, 256, 0, stream>>>(W_fc, wfcb, ODIM * GRU_H);
  k_cvt_pad<<<512, 256, 0, stream>>>(input, decb, BATCH, ODIM, PADX);
  k_init_h<<<2048, 256, 0, stream>>>(hiddens, h0f[0], h0b[0], BATCH * GRU_H);
  k_init_h<<<2048, 256, 0, stream>>>(hiddens + (size_t)BATCH * GRU_H, h1f[0], h1b[0], BATCH * GRU_H);

  int cur = 0;
  for (int t = 0; t < TSTEPS; ++t) {
    int nxt = cur ^ 1;
    k_gru<<<dim3(32, 8), 512, 0, stream>>>(decb, PADX, h0b[cur], wih0f, whh0f,
                                           b_ih0, b_hh0, h0f[cur], h0f[nxt], h0b[nxt]);
    k_gru<<<dim3(32, 8), 512, 0, stream>>>(h0b[nxt], GRU_H, h1b[cur], wih1f, whh1f,
                                           b_ih1, b_hh1, h1f[cur], h1f[nxt], h1b[nxt]);
    k_fc_part<<<dim3(16, 16), 256, 0, stream>>>(h1b[nxt], wfcb, fcpart);
    k_fc_red<<<384, 256, 0, stream>>>(fcpart, b_fc, out, decb, t);
    cur = nxt;
  }
}